// Round 5
// baseline (50.961 us; speedup 1.0000x reference)
//
#include <hip/hip_runtime.h>

#define D_DIM 64
#define N_ROT 128

typedef float v4f __attribute__((ext_vector_type(4)));

// One wave per block; chunk = 32 rows x 64 cols (8 KB). TWO lanes per row:
// lane l = 2r+h owns columns [h*32, h*32+32) of row r in v[0..31].
// Rotation chain crosses the half boundary only at k%32==31 -> 4 shfl_xor
// per chunk. Same software pipeline as before (loads for t+1/t+2 in flight
// during compute(t), counted vmcnt so stores are never waited on), but the
// halved LDS footprint (17.4 KB) doubles residency to 8 waves/CU.
__global__ __launch_bounds__(64) void givens_kernel(
    const float* __restrict__ x,
    const float* __restrict__ thetas,
    float* __restrict__ out,
    int nchunks)
{
    __shared__ __align__(16) float bufA[32 * D_DIM];   // load staging  (8 KiB)
    __shared__ __align__(16) float bufB[32 * D_DIM];   // store staging (8 KiB)
    __shared__ float2 cs_tab[N_ROT];                   // {cos,sin}, 1 KiB

    const int l  = threadIdx.x;      // 0..63
    const int r  = l >> 1;           // row within chunk, 0..31
    const int h  = l & 1;            // which half of the row
    const int r7 = r & 7;

    {   // per-block cos/sin table
        const float tha = thetas[l];
        const float thb = thetas[l + 64];
        cs_tab[l]      = make_float2(cosf(tha), sinf(tha));
        cs_tab[l + 64] = make_float2(cosf(thb), sinf(thb));
    }
    asm volatile("s_waitcnt lgkmcnt(0)" ::: "memory");

    // Contiguous chunk range per block.
    const int cpb = (nchunks + gridDim.x - 1) / gridDim.x;
    const int c0  = blockIdx.x * cpb;
    const int c1  = (c0 + cpb < nchunks) ? (c0 + cpb) : nchunks;
    if (c0 >= c1) return;

    // Slot swizzle: phys16 = (v&8) | ((v&7) ^ (row&7))  (involution; maps
    // aligned 4-slot groups to aligned 4-slot groups -> 64B lines intact).
    // STAGE: linear LDS dest (q*1024 + l*16), inverse-swizzled global source.
    auto STAGE = [&](int c) {
        const char* g = (const char*)(x + (size_t)c * (32 * D_DIM));
        #pragma unroll
        for (int q = 0; q < 8; ++q) {
            const int row = q * 4 + (l >> 4);
            const int p   = l & 15;
            const int vs  = (p & 8) | ((p & 7) ^ (row & 7));
            __builtin_amdgcn_global_load_lds(
                (const __attribute__((address_space(1))) void*)(g + row * 256 + vs * 16),
                (__attribute__((address_space(3))) void*)((char*)bufA + q * 1024),
                16, 0, 0);
        }
    };

    float v[32];

    // Gather own half-row from bufA (8-words/bank floor, conflict-free).
    auto GATHER = [&]() {
        #pragma unroll
        for (int g = 0; g < 8; ++g) {
            const int ph = (h << 3) | (g ^ r7);
            const float4 t = *reinterpret_cast<const float4*>(&bufA[r * D_DIM + ph * 4]);
            v[4 * g + 0] = t.x; v[4 * g + 1] = t.y;
            v[4 * g + 2] = t.z; v[4 * g + 3] = t.w;
        }
    };

    // ---- Prologue.
    STAGE(c0);
    asm volatile("s_waitcnt vmcnt(0)" ::: "memory");
    GATHER();
    asm volatile("s_waitcnt lgkmcnt(0)" ::: "memory");
    if (c0 + 1 < c1) STAGE(c0 + 1);

    for (int c = c0; c < c1; ++c) {
        // ---- 128 chained rotations. Interior rotations predicated by half;
        // boundary rotations (i&31 == 31) exchange one value with the
        // partner lane (l^1).
        #pragma unroll
        for (int k = 0; k < N_ROT; ++k) {
            const int i = k & (D_DIM - 1);
            const float2 cs = cs_tab[k];
            const float cc = cs.x, ss = cs.y;
            if ((i & 31) != 31) {
                const int  li  = i & 31;
                const bool act = (h == (i >> 5));
                const float xi = v[li], xj = v[li + 1];
                const float ni = fmaf(cc, xi, ss * xj);
                const float nj = fmaf(-ss, xi, cc * xj);
                v[li]     = act ? ni : v[li];
                v[li + 1] = act ? nj : v[li + 1];
            } else if (i == 31) {
                // cols (31, 32): h0 holds col31 = v[31], h1 holds col32 = v[0]
                const float other = __shfl_xor(h ? v[0] : v[31], 1);
                const float xi = h ? other : v[31];
                const float xj = h ? v[0]  : other;
                const float ni = fmaf(cc, xi, ss * xj);    // new col31 (h0)
                const float nj = fmaf(-ss, xi, cc * xj);   // new col32 (h1)
                v[31] = h ? v[31] : ni;
                v[0]  = h ? nj    : v[0];
            } else { // i == 63, cols (63, 0)
                const float other = __shfl_xor(h ? v[31] : v[0], 1);
                const float xi = h ? v[31] : other;
                const float xj = h ? other : v[0];
                const float ni = fmaf(cc, xi, ss * xj);    // new col63 (h1)
                const float nj = fmaf(-ss, xi, cc * xj);   // new col0  (h0)
                v[31] = h ? ni   : v[31];
                v[0]  = h ? v[0] : nj;
            }
        }

        // ---- Transpose out through bufB (same swizzled slots).
        #pragma unroll
        for (int g = 0; g < 8; ++g) {
            const int ph = (h << 3) | (g ^ r7);
            float4 t;
            t.x = v[4 * g + 0]; t.y = v[4 * g + 1];
            t.z = v[4 * g + 2]; t.w = v[4 * g + 3];
            *reinterpret_cast<float4*>(&bufB[r * D_DIM + ph * 4]) = t;
        }
        asm volatile("s_waitcnt lgkmcnt(0)" ::: "memory");

        // ---- Drain bufB -> global (linear LDS read, line-coalesced nt stores).
        {
            char* gout = (char*)(out + (size_t)c * (32 * D_DIM));
            #pragma unroll
            for (int q = 0; q < 8; ++q) {
                const int row = q * 4 + (l >> 4);
                const int p   = l & 15;
                const int vs  = (p & 8) | ((p & 7) ^ (row & 7));
                const v4f t = *reinterpret_cast<const v4f*>(&bufB[q * 256 + l * 4]);
                __builtin_nontemporal_store(
                    t, reinterpret_cast<v4f*>(gout + row * 256 + vs * 16));
            }
        }

        if (c + 1 < c1) {
            // FIFO: L(c+1)[8] then S(c)[8]; vmcnt(8) retires all of L(c+1)
            // while leaving the 8 stores in flight.
            asm volatile("s_waitcnt vmcnt(8)" ::: "memory");
            GATHER();
            asm volatile("s_waitcnt lgkmcnt(0)" ::: "memory");  // bufA free
            if (c + 2 < c1) STAGE(c + 2);
        }
    }
}

extern "C" void kernel_launch(void* const* d_in, const int* in_sizes, int n_in,
                              void* d_out, int out_size, void* d_ws, size_t ws_size,
                              hipStream_t stream) {
    const float* x      = (const float*)d_in[0];
    const float* thetas = (const float*)d_in[1];
    float* out          = (float*)d_out;

    const int nrows   = in_sizes[0] / D_DIM;   // 524288
    const int nchunks = nrows / 32;            // 16384

    // 8 blocks/CU resident (17.4 KiB LDS each) x 256 CUs; 8 chunks/block.
    int grid = 8 * 256;
    if (grid > nchunks) grid = nchunks;

    givens_kernel<<<grid, 64, 0, stream>>>(x, thetas, out, nchunks);
}

// Round 6
// 50.928 us; speedup vs baseline: 1.0006x; 1.0006x over previous
//
#include <hip/hip_runtime.h>

#define D_DIM 64
#define N_ROT 128

typedef float v4f __attribute__((ext_vector_type(4)));

// One wave (64 lanes) per block; lane l owns row l of a 64-row chunk.
// Software-pipelined: loads for chunk t+1 (and t+2) are in flight while
// chunk t computes; counted vmcnt so stores are never waited on.
__global__ __launch_bounds__(64) void givens_kernel(
    const float* __restrict__ x,
    const float* __restrict__ thetas,
    float* __restrict__ out,
    int nchunks)
{
    __shared__ __align__(16) float bufA[64 * D_DIM];   // load staging  (16 KiB)
    __shared__ __align__(16) float bufB[64 * D_DIM];   // store staging (16 KiB)
    __shared__ float2 cs_tab[N_ROT];                   // {cos,sin}, 1 KiB

    const int l    = threadIdx.x;    // 0..63
    const int lo16 = l & 15;

    {   // per-block cos/sin table
        const float tha = thetas[l];
        const float thb = thetas[l + 64];
        cs_tab[l]      = make_float2(cosf(tha), sinf(tha));
        cs_tab[l + 64] = make_float2(cosf(thb), sinf(thb));
    }
    asm volatile("s_waitcnt lgkmcnt(0)" ::: "memory");

    // Contiguous chunk range per block.
    const int cpb = (nchunks + gridDim.x - 1) / gridDim.x;
    const int c0  = blockIdx.x * cpb;
    const int c1  = (c0 + cpb < nchunks) ? (c0 + cpb) : nchunks;
    if (c0 >= c1) return;

    // Stage chunk -> bufA: linear LDS dest, XOR-pre-swizzled global source
    // (involution on 16B slots within each 256B row; 64B lines stay intact).
    auto STAGE = [&](int c) {
        const char* g = (const char*)(x + (size_t)c * (64 * D_DIM));
        #pragma unroll
        for (int q = 0; q < 16; ++q) {
            const int r  = q * 4 + (l >> 4);
            const int gs = lo16 ^ (r & 15);
            __builtin_amdgcn_global_load_lds(
                (const __attribute__((address_space(1))) void*)(g + r * 256 + gs * 16),
                (__attribute__((address_space(3))) void*)((char*)bufA + q * 1024),
                16, 0, 0);
        }
    };

    float v[D_DIM];

    // Gather own row from bufA (swizzled ds_read_b128, conflict-free).
    auto GATHER = [&]() {
        #pragma unroll
        for (int g = 0; g < 16; ++g) {
            const int sl = g ^ lo16;
            const float4 t = *reinterpret_cast<const float4*>(&bufA[l * D_DIM + sl * 4]);
            v[4 * g + 0] = t.x; v[4 * g + 1] = t.y;
            v[4 * g + 2] = t.z; v[4 * g + 3] = t.w;
        }
    };

    // ---- Prologue: fill regs with chunk c0; put chunk c0+1 in flight.
    STAGE(c0);
    asm volatile("s_waitcnt vmcnt(0)" ::: "memory");
    GATHER();
    asm volatile("s_waitcnt lgkmcnt(0)" ::: "memory");
    if (c0 + 1 < c1) STAGE(c0 + 1);

    for (int c = c0; c < c1; ++c) {
        // ---- 128 chained rotations; 1 dependent fma per rotation on the
        // critical path (the independent muls hoist above the chain).
        #pragma unroll
        for (int k = 0; k < N_ROT; ++k) {
            const int i = k & (D_DIM - 1);
            const int j = (k + 1) & (D_DIM - 1);
            const float2 cs = cs_tab[k];
            const float xi = v[i], xj = v[j];
            v[i] = fmaf(cs.x, xi, cs.y * xj);
            v[j] = fmaf(-cs.y, xi, cs.x * xj);
        }

        // ---- Transpose out through bufB (same swizzle).
        #pragma unroll
        for (int g = 0; g < 16; ++g) {
            const int sl = g ^ lo16;
            float4 t;
            t.x = v[4 * g + 0]; t.y = v[4 * g + 1];
            t.z = v[4 * g + 2]; t.w = v[4 * g + 3];
            *reinterpret_cast<float4*>(&bufB[l * D_DIM + sl * 4]) = t;
        }
        asm volatile("s_waitcnt lgkmcnt(0)" ::: "memory");

        // ---- Drain bufB -> global (linear LDS read, line-coalesced stores).
        {
            char* gout = (char*)(out + (size_t)c * (64 * D_DIM));
            #pragma unroll
            for (int q = 0; q < 16; ++q) {
                const int r  = q * 4 + (l >> 4);
                const int gs = lo16 ^ (r & 15);
                const v4f t = *reinterpret_cast<const v4f*>(&bufB[q * 256 + l * 4]);
                *reinterpret_cast<v4f*>(gout + r * 256 + gs * 16) = t;
            }
        }

        if (c + 1 < c1) {
            // FIFO: L(c+1)[16 oldest] then S(c)[16]. vmcnt(16) retires all of
            // L(c+1) while leaving the 16 stores in flight.
            asm volatile("s_waitcnt vmcnt(16)" ::: "memory");
            GATHER();
            asm volatile("s_waitcnt lgkmcnt(0)" ::: "memory");  // bufA free
            if (c + 2 < c1) STAGE(c + 2);
        }
    }
}

extern "C" void kernel_launch(void* const* d_in, const int* in_sizes, int n_in,
                              void* d_out, int out_size, void* d_ws, size_t ws_size,
                              hipStream_t stream) {
    const float* x      = (const float*)d_in[0];
    const float* thetas = (const float*)d_in[1];
    float* out          = (float*)d_out;

    const int nrows   = in_sizes[0] / D_DIM;   // 524288
    const int nchunks = nrows / 64;            // 8192

    // 4 blocks/CU resident (33.8 KiB LDS each); grid 2048 -> 4 more queued
    // per CU for backfill (de-phases bursts, shrinks the tail quantum).
    int grid = 2048;
    if (grid > nchunks) grid = nchunks;

    givens_kernel<<<grid, 64, 0, stream>>>(x, thetas, out, nchunks);
}

// Round 7
// 48.766 us; speedup vs baseline: 1.0450x; 1.0443x over previous
//
#include <hip/hip_runtime.h>

#define D_DIM 64
#define N_ROT 128

typedef float v4f __attribute__((ext_vector_type(4)));

// One wave (64 lanes) per block; lane l owns row l of a 64-row chunk.
// Software-pipelined: loads for chunk t+1 (and t+2) are in flight while
// chunk t computes; counted vmcnt so stores are never waited on.
// NT stores on the drain path (best measured config, R3: 48.6 us).
__global__ __launch_bounds__(64) void givens_kernel(
    const float* __restrict__ x,
    const float* __restrict__ thetas,
    float* __restrict__ out,
    int nchunks)
{
    __shared__ __align__(16) float bufA[64 * D_DIM];   // load staging  (16 KiB)
    __shared__ __align__(16) float bufB[64 * D_DIM];   // store staging (16 KiB)
    __shared__ float2 cs_tab[N_ROT];                   // {cos,sin}, 1 KiB

    const int l    = threadIdx.x;    // 0..63
    const int lo16 = l & 15;

    {   // per-block cos/sin table
        const float tha = thetas[l];
        const float thb = thetas[l + 64];
        cs_tab[l]      = make_float2(cosf(tha), sinf(tha));
        cs_tab[l + 64] = make_float2(cosf(thb), sinf(thb));
    }
    asm volatile("s_waitcnt lgkmcnt(0)" ::: "memory");

    // Contiguous chunk range per block (2 MB per block: long DRAM streams).
    const int cpb = (nchunks + gridDim.x - 1) / gridDim.x;
    const int c0  = blockIdx.x * cpb;
    const int c1  = (c0 + cpb < nchunks) ? (c0 + cpb) : nchunks;
    if (c0 >= c1) return;

    // Stage chunk -> bufA: linear LDS dest, XOR-pre-swizzled global source
    // (involution on 16B slots within each 256B row; 64B lines stay intact).
    auto STAGE = [&](int c) {
        const char* g = (const char*)(x + (size_t)c * (64 * D_DIM));
        #pragma unroll
        for (int q = 0; q < 16; ++q) {
            const int r  = q * 4 + (l >> 4);
            const int gs = lo16 ^ (r & 15);
            __builtin_amdgcn_global_load_lds(
                (const __attribute__((address_space(1))) void*)(g + r * 256 + gs * 16),
                (__attribute__((address_space(3))) void*)((char*)bufA + q * 1024),
                16, 0, 0);
        }
    };

    float v[D_DIM];

    // Gather own row from bufA (swizzled ds_read_b128, conflict-free).
    auto GATHER = [&]() {
        #pragma unroll
        for (int g = 0; g < 16; ++g) {
            const int sl = g ^ lo16;
            const float4 t = *reinterpret_cast<const float4*>(&bufA[l * D_DIM + sl * 4]);
            v[4 * g + 0] = t.x; v[4 * g + 1] = t.y;
            v[4 * g + 2] = t.z; v[4 * g + 3] = t.w;
        }
    };

    // ---- Prologue: fill regs with chunk c0; put chunk c0+1 in flight.
    STAGE(c0);
    asm volatile("s_waitcnt vmcnt(0)" ::: "memory");
    GATHER();
    asm volatile("s_waitcnt lgkmcnt(0)" ::: "memory");
    if (c0 + 1 < c1) STAGE(c0 + 1);

    for (int c = c0; c < c1; ++c) {
        // ---- 128 chained rotations; 1 dependent fma per rotation on the
        // critical path (the independent muls hoist above the chain).
        #pragma unroll
        for (int k = 0; k < N_ROT; ++k) {
            const int i = k & (D_DIM - 1);
            const int j = (k + 1) & (D_DIM - 1);
            const float2 cs = cs_tab[k];
            const float xi = v[i], xj = v[j];
            v[i] = fmaf(cs.x, xi, cs.y * xj);
            v[j] = fmaf(-cs.y, xi, cs.x * xj);
        }

        // ---- Transpose out through bufB (same swizzle).
        #pragma unroll
        for (int g = 0; g < 16; ++g) {
            const int sl = g ^ lo16;
            float4 t;
            t.x = v[4 * g + 0]; t.y = v[4 * g + 1];
            t.z = v[4 * g + 2]; t.w = v[4 * g + 3];
            *reinterpret_cast<float4*>(&bufB[l * D_DIM + sl * 4]) = t;
        }
        asm volatile("s_waitcnt lgkmcnt(0)" ::: "memory");

        // ---- Drain bufB -> global (linear LDS read, line-coalesced nt stores).
        {
            char* gout = (char*)(out + (size_t)c * (64 * D_DIM));
            #pragma unroll
            for (int q = 0; q < 16; ++q) {
                const int r  = q * 4 + (l >> 4);
                const int gs = lo16 ^ (r & 15);
                const v4f t = *reinterpret_cast<const v4f*>(&bufB[q * 256 + l * 4]);
                __builtin_nontemporal_store(
                    t, reinterpret_cast<v4f*>(gout + r * 256 + gs * 16));
            }
        }

        if (c + 1 < c1) {
            // FIFO: L(c+1)[16 oldest] then S(c)[16]. vmcnt(16) retires all of
            // L(c+1) while leaving the 16 stores in flight.
            asm volatile("s_waitcnt vmcnt(16)" ::: "memory");
            GATHER();
            asm volatile("s_waitcnt lgkmcnt(0)" ::: "memory");  // bufA free
            if (c + 2 < c1) STAGE(c + 2);
        }
    }
}

extern "C" void kernel_launch(void* const* d_in, const int* in_sizes, int n_in,
                              void* d_out, int out_size, void* d_ws, size_t ws_size,
                              hipStream_t stream) {
    const float* x      = (const float*)d_in[0];
    const float* thetas = (const float*)d_in[1];
    float* out          = (float*)d_out;

    const int nrows   = in_sizes[0] / D_DIM;   // 524288
    const int nchunks = nrows / 64;            // 8192

    // 4 blocks/CU resident (33.8 KiB LDS each) x 256 CUs = 1024 blocks,
    // 8 chunks (2 MB) per block. Best measured config (R3).
    int grid = 4 * 256;
    if (grid > nchunks) grid = nchunks;

    givens_kernel<<<grid, 64, 0, stream>>>(x, thetas, out, nchunks);
}